// Round 1
// baseline (552.961 us; speedup 1.0000x reference)
//
#include <hip/hip_runtime.h>
#include <math.h>

// CoordinateDecoder: coords[8,256,256,2] f32 -> out[8,256,256,4] f32
// Strategy: hoist the conditioning (per-batch-constant) half of every layer
// into precomputed biases; fold equal-lr scale + freq mask into weights.
// Main kernel: 21k FLOP/pixel pure-VALU fp32 MLP, weights via uniform
// (scalarized) loads, activations in VGPRs.

#define SCALE1 0.0790569415042094833f  // 1/sqrt(160)
#define SCALE2 0.0721687836487032206f  // 1/sqrt(192)
#define SQRT2F 1.41421356237309515f

// ws layout (float offsets)
#define OFF_W1  0       // [64][32] masked+scaled
#define OFF_W2  2048    // [64][64] scaled
#define OFF_W3  6144    // [64][64] scaled
#define OFF_W4  10240   // [4][64]  scaled
#define OFF_CB1 10496   // [8][64]  cond bias layer1 (incl b1)
#define OFF_CB2 11008   // [8][64]
#define OFF_CB3 11520   // [8][64]
#define OFF_CB4 12032   // [8][4]
// total 12064 floats = 48256 bytes

__global__ __launch_bounds__(256) void prep_kernel(
    const float* __restrict__ c, const float* __restrict__ fu,
    const float* __restrict__ w1, const float* __restrict__ b1,
    const float* __restrict__ w2, const float* __restrict__ b2,
    const float* __restrict__ w3, const float* __restrict__ b3,
    const float* __restrict__ w4, const float* __restrict__ b4,
    float* __restrict__ ws)
{
  int t = blockIdx.x * 256 + threadIdx.x;
  if (t < 2048) {
    // w1 emb part, with progressive frequency mask folded in
    int j = t >> 5, k = t & 31;
    float mw = (fu[0] - (float)((k >> 2) + 1) * (1.0f / 9.0f)) * 9.0f;
    mw = fminf(fmaxf(mw, 0.0f), 1.0f);
    ws[OFF_W1 + t] = w1[j * 160 + k] * SCALE1 * mw;
  } else if (t < 6144) {
    int t2 = t - 2048; int j = t2 >> 6, k = t2 & 63;
    ws[OFF_W2 + t2] = w2[j * 192 + k] * SCALE2;
  } else if (t < 10240) {
    int t2 = t - 6144; int j = t2 >> 6, k = t2 & 63;
    ws[OFF_W3 + t2] = w3[j * 192 + k] * SCALE2;
  } else if (t < 10496) {
    int t2 = t - 10240; int j = t2 >> 6, k = t2 & 63;
    ws[OFF_W4 + t2] = w4[j * 192 + k] * SCALE2;
  } else if (t < 10496 + 1568) {
    // per-(batch, output) conditioning dot products
    int u = t - 10496;
    int b = u / 196, r = u - b * 196;
    const float* cb = c + b * 128;
    float acc;
    if (r < 64) {
      acc = b1[r];
      const float* wr = w1 + r * 160 + 32;
      #pragma unroll 8
      for (int k = 0; k < 128; ++k) acc = fmaf(wr[k] * SCALE1, cb[k], acc);
      ws[OFF_CB1 + b * 64 + r] = acc;
    } else if (r < 128) {
      int j = r - 64;
      acc = b2[j];
      const float* wr = w2 + j * 192 + 64;
      #pragma unroll 8
      for (int k = 0; k < 128; ++k) acc = fmaf(wr[k] * SCALE2, cb[k], acc);
      ws[OFF_CB2 + b * 64 + j] = acc;
    } else if (r < 192) {
      int j = r - 128;
      acc = b3[j];
      const float* wr = w3 + j * 192 + 64;
      #pragma unroll 8
      for (int k = 0; k < 128; ++k) acc = fmaf(wr[k] * SCALE2, cb[k], acc);
      ws[OFF_CB3 + b * 64 + j] = acc;
    } else {
      int j = r - 192;
      acc = b4[j];
      const float* wr = w4 + j * 192 + 64;
      #pragma unroll 8
      for (int k = 0; k < 128; ++k) acc = fmaf(wr[k] * SCALE2, cb[k], acc);
      ws[OFF_CB4 + b * 4 + j] = acc;
    }
  }
}

__global__ __launch_bounds__(256) void decoder_main(
    const float* __restrict__ coords, const float* __restrict__ ws,
    float4* __restrict__ out, int npix)
{
  int i = blockIdx.x * 256 + threadIdx.x;
  if (i >= npix) return;
  const float2* c2 = (const float2*)coords;
  float2 cc = c2[i];
  float cx = cc.x, cy = cc.y;
  int b = i >> 16;  // 65536 pixels per batch image

  // sinusoidal embedding of coords/10, blocks [sin x, sin y, cos x, cos y]
  float x[32];
  float ax = cx * 0.1f, ay = cy * 0.1f;
  #pragma unroll
  for (int f = 0; f < 8; ++f) {
    x[4 * f + 0] = __sinf(ax);
    x[4 * f + 1] = __sinf(ay);
    x[4 * f + 2] = __cosf(ax);
    x[4 * f + 3] = __cosf(ay);
    ax += ax; ay += ay;
  }

  const float* w1f = ws + OFF_W1;
  const float* w2f = ws + OFF_W2;
  const float* w3f = ws + OFF_W3;
  const float* w4f = ws + OFF_W4;
  const float* cb1 = ws + OFF_CB1 + b * 64;
  const float* cb2 = ws + OFF_CB2 + b * 64;
  const float* cb3 = ws + OFF_CB3 + b * 64;
  const float* cb4 = ws + OFF_CB4 + b * 4;

  float h1[64];
  #pragma unroll 4
  for (int j = 0; j < 64; ++j) {
    float acc = cb1[j];
    #pragma unroll
    for (int k = 0; k < 32; ++k) acc = fmaf(w1f[j * 32 + k], x[k], acc);
    h1[j] = (acc > 0.0f ? acc : 0.2f * acc) * SQRT2F;
  }

  float h2[64];
  #pragma unroll 4
  for (int j = 0; j < 64; ++j) {
    float acc = cb2[j];
    #pragma unroll
    for (int k = 0; k < 64; ++k) acc = fmaf(w2f[j * 64 + k], h1[k], acc);
    h2[j] = (acc > 0.0f ? acc : 0.2f * acc) * SQRT2F;
  }

  // h3 overwrites h1 to cap live registers at ~2x64
  #pragma unroll 4
  for (int j = 0; j < 64; ++j) {
    float acc = cb3[j];
    #pragma unroll
    for (int k = 0; k < 64; ++k) acc = fmaf(w3f[j * 64 + k], h2[k], acc);
    h1[j] = (acc > 0.0f ? acc : 0.2f * acc) * SQRT2F;
  }

  float o[4];
  #pragma unroll
  for (int j = 0; j < 4; ++j) {
    float acc = cb4[j];
    #pragma unroll
    for (int k = 0; k < 64; ++k) acc = fmaf(w4f[j * 64 + k], h1[k], acc);
    o[j] = acc;
  }

  // radius mask: 1 - tanh(relu(r-1)) == 2/(exp(2*max(r-1,0))+1)
  float r = sqrtf(cx * cx + cy * cy);
  float tt = fmaxf(r - 1.0f, 0.0f);
  float m = 2.0f / (__expf(2.0f * tt) + 1.0f);

  out[i] = make_float4(o[0] * m, o[1] * m, o[2] * m, o[3] * m);
}

extern "C" void kernel_launch(void* const* d_in, const int* in_sizes, int n_in,
                              void* d_out, int out_size, void* d_ws, size_t ws_size,
                              hipStream_t stream) {
  const float* coords = (const float*)d_in[0];
  const float* c      = (const float*)d_in[1];
  const float* fu     = (const float*)d_in[2];
  const float* w1     = (const float*)d_in[3];
  const float* b1     = (const float*)d_in[4];
  const float* w2     = (const float*)d_in[5];
  const float* b2     = (const float*)d_in[6];
  const float* w3     = (const float*)d_in[7];
  const float* b3     = (const float*)d_in[8];
  const float* w4     = (const float*)d_in[9];
  const float* b4     = (const float*)d_in[10];
  float* ws  = (float*)d_ws;
  float* out = (float*)d_out;

  int npix = in_sizes[0] / 2;  // 8*256*256 = 524288

  prep_kernel<<<48, 256, 0, stream>>>(c, fu, w1, b1, w2, b2, w3, b3, w4, b4, ws);
  decoder_main<<<(npix + 255) / 256, 256, 0, stream>>>(coords, ws, (float4*)out, npix);
}

// Round 3
// 259.235 us; speedup vs baseline: 2.1330x; 2.1330x over previous
//
#include <hip/hip_runtime.h>
#include <math.h>

// CoordinateDecoder: coords[8,256,256,2] f32 -> out[8,256,256,4] f32
// R3: activations live in LDS as per-thread scratch (dynamic k-index legal),
// accumulators are statically-indexed registers (j-loop unrolled, k-loop
// runtime). Weights pre-transposed to [k][j] so the inner 64 weights are a
// wave-uniform contiguous row -> s_load_dwordx16 (scalar pipe, free).
// Avoids both R1's scratch spills and R2's 100KB mega-unroll.

#define SCALE1 0.0790569415042094833f  // 1/sqrt(160)
#define SCALE2 0.0721687836487032206f  // 1/sqrt(192)
#define SQRT2F 1.41421356237309515f
#define BLOCK 128

// ws layout (float offsets) — weights TRANSPOSED to [k][j]
#define OFF_W1T 0       // [32][64] masked+scaled
#define OFF_W2T 2048    // [64][64] scaled (pixel-half of w2)
#define OFF_W3T 6144    // [64][64] scaled
#define OFF_W4T 10240   // [64][4]  scaled
#define OFF_CB1 10496   // [8][64]  cond bias layer1 (incl b1)
#define OFF_CB2 11008   // [8][64]
#define OFF_CB3 11520   // [8][64]
#define OFF_CB4 12032   // [8][4]
// total 12064 floats = 48256 bytes

__global__ __launch_bounds__(256) void prep_kernel(
    const float* __restrict__ c, const float* __restrict__ fu,
    const float* __restrict__ w1, const float* __restrict__ b1,
    const float* __restrict__ w2, const float* __restrict__ b2,
    const float* __restrict__ w3, const float* __restrict__ b3,
    const float* __restrict__ w4, const float* __restrict__ b4,
    float* __restrict__ ws)
{
  int t = blockIdx.x * 256 + threadIdx.x;
  if (t < 2048) {
    // w1 pixel part, transposed, with progressive frequency mask folded in
    int k = t >> 6, j = t & 63;
    float mw = (fu[0] - (float)((k >> 2) + 1) * (1.0f / 9.0f)) * 9.0f;
    mw = fminf(fmaxf(mw, 0.0f), 1.0f);
    ws[OFF_W1T + t] = w1[j * 160 + k] * SCALE1 * mw;
  } else if (t < 6144) {
    int u = t - 2048; int k = u >> 6, j = u & 63;
    ws[OFF_W2T + u] = w2[j * 192 + k] * SCALE2;
  } else if (t < 10240) {
    int u = t - 6144; int k = u >> 6, j = u & 63;
    ws[OFF_W3T + u] = w3[j * 192 + k] * SCALE2;
  } else if (t < 10496) {
    int u = t - 10240; int k = u >> 2, j = u & 3;
    ws[OFF_W4T + u] = w4[j * 192 + k] * SCALE2;
  } else if (t < 10496 + 1568) {
    // per-(batch, output) conditioning dot products
    int u = t - 10496;
    int b = u / 196, r = u - b * 196;
    const float* cb = c + b * 128;
    float acc;
    if (r < 64) {
      acc = b1[r];
      const float* wr = w1 + r * 160 + 32;
      #pragma unroll 8
      for (int k = 0; k < 128; ++k) acc = fmaf(wr[k] * SCALE1, cb[k], acc);
      ws[OFF_CB1 + b * 64 + r] = acc;
    } else if (r < 128) {
      int j = r - 64;
      acc = b2[j];
      const float* wr = w2 + j * 192 + 64;
      #pragma unroll 8
      for (int k = 0; k < 128; ++k) acc = fmaf(wr[k] * SCALE2, cb[k], acc);
      ws[OFF_CB2 + b * 64 + j] = acc;
    } else if (r < 192) {
      int j = r - 128;
      acc = b3[j];
      const float* wr = w3 + j * 192 + 64;
      #pragma unroll 8
      for (int k = 0; k < 128; ++k) acc = fmaf(wr[k] * SCALE2, cb[k], acc);
      ws[OFF_CB3 + b * 64 + j] = acc;
    } else {
      int j = r - 192;
      acc = b4[j];
      const float* wr = w4 + j * 192 + 64;
      #pragma unroll 8
      for (int k = 0; k < 128; ++k) acc = fmaf(wr[k] * SCALE2, cb[k], acc);
      ws[OFF_CB4 + b * 4 + j] = acc;
    }
  }
}

__global__ __launch_bounds__(BLOCK) void decoder_main(
    const float* __restrict__ coords, const float* __restrict__ ws,
    float4* __restrict__ out, int npix)
{
  __shared__ float act[64 * BLOCK];  // act[k][tid], conflict-free
  const int tid = threadIdx.x;
  const int i = blockIdx.x * BLOCK + tid;
  if (i >= npix) return;
  // batch index is block-uniform (65536 px per image, 512 blocks per image)
  const int b = (blockIdx.x * BLOCK) >> 16;

  const float2 cc = ((const float2*)coords)[i];
  const float cx = cc.x, cy = cc.y;

  // sinusoidal embedding of coords/10 -> act[0..31]
  float ax = cx * 0.1f, ay = cy * 0.1f;
  #pragma unroll
  for (int f = 0; f < 8; ++f) {
    act[(4 * f + 0) * BLOCK + tid] = __sinf(ax);
    act[(4 * f + 1) * BLOCK + tid] = __sinf(ay);
    act[(4 * f + 2) * BLOCK + tid] = __cosf(ax);
    act[(4 * f + 3) * BLOCK + tid] = __cosf(ay);
    ax += ax; ay += ay;
  }

  const float* __restrict__ cb1 = ws + OFF_CB1 + b * 64;
  const float* __restrict__ cb2 = ws + OFF_CB2 + b * 64;
  const float* __restrict__ cb3 = ws + OFF_CB3 + b * 64;
  const float* __restrict__ cb4 = ws + OFF_CB4 + b * 4;

  float acc[64];

  // ---- layer 1: 32 -> 64 ----
  #pragma unroll
  for (int j = 0; j < 64; ++j) acc[j] = cb1[j];
  for (int k = 0; k < 32; ++k) {
    const float a = act[k * BLOCK + tid];
    const float* __restrict__ wr = ws + OFF_W1T + k * 64;
    #pragma unroll
    for (int j = 0; j < 64; ++j) acc[j] = fmaf(wr[j], a, acc[j]);
  }
  #pragma unroll
  for (int j = 0; j < 64; ++j) {
    float v = acc[j];
    v = (v > 0.0f ? v : 0.2f * v) * SQRT2F;
    act[j * BLOCK + tid] = v;
    acc[j] = cb2[j];
  }

  // ---- layer 2: 64 -> 64 ----
  for (int k = 0; k < 64; ++k) {
    const float a = act[k * BLOCK + tid];
    const float* __restrict__ wr = ws + OFF_W2T + k * 64;
    #pragma unroll
    for (int j = 0; j < 64; ++j) acc[j] = fmaf(wr[j], a, acc[j]);
  }
  #pragma unroll
  for (int j = 0; j < 64; ++j) {
    float v = acc[j];
    v = (v > 0.0f ? v : 0.2f * v) * SQRT2F;
    act[j * BLOCK + tid] = v;
    acc[j] = cb3[j];
  }

  // ---- layer 3: 64 -> 64 ----
  for (int k = 0; k < 64; ++k) {
    const float a = act[k * BLOCK + tid];
    const float* __restrict__ wr = ws + OFF_W3T + k * 64;
    #pragma unroll
    for (int j = 0; j < 64; ++j) acc[j] = fmaf(wr[j], a, acc[j]);
  }
  #pragma unroll
  for (int j = 0; j < 64; ++j) {
    float v = acc[j];
    v = (v > 0.0f ? v : 0.2f * v) * SQRT2F;
    act[j * BLOCK + tid] = v;
  }

  // ---- layer 4: 64 -> 4 ----
  float o0 = cb4[0], o1 = cb4[1], o2 = cb4[2], o3 = cb4[3];
  for (int k = 0; k < 64; ++k) {
    const float a = act[k * BLOCK + tid];
    const float* __restrict__ wr = ws + OFF_W4T + k * 4;
    o0 = fmaf(wr[0], a, o0);
    o1 = fmaf(wr[1], a, o1);
    o2 = fmaf(wr[2], a, o2);
    o3 = fmaf(wr[3], a, o3);
  }

  // radius mask: 1 - tanh(relu(r-1)) == 2/(exp(2*max(r-1,0))+1)
  const float r = sqrtf(cx * cx + cy * cy);
  const float tt = fmaxf(r - 1.0f, 0.0f);
  const float m = 2.0f / (__expf(2.0f * tt) + 1.0f);

  out[i] = make_float4(o0 * m, o1 * m, o2 * m, o3 * m);
}

extern "C" void kernel_launch(void* const* d_in, const int* in_sizes, int n_in,
                              void* d_out, int out_size, void* d_ws, size_t ws_size,
                              hipStream_t stream) {
  const float* coords = (const float*)d_in[0];
  const float* c      = (const float*)d_in[1];
  const float* fu     = (const float*)d_in[2];
  const float* w1     = (const float*)d_in[3];
  const float* b1     = (const float*)d_in[4];
  const float* w2     = (const float*)d_in[5];
  const float* b2     = (const float*)d_in[6];
  const float* w3     = (const float*)d_in[7];
  const float* b3     = (const float*)d_in[8];
  const float* w4     = (const float*)d_in[9];
  const float* b4     = (const float*)d_in[10];
  float* ws  = (float*)d_ws;
  float* out = (float*)d_out;

  int npix = in_sizes[0] / 2;  // 8*256*256 = 524288

  prep_kernel<<<48, 256, 0, stream>>>(c, fu, w1, b1, w2, b2, w3, b3, w4, b4, ws);
  decoder_main<<<(npix + BLOCK - 1) / BLOCK, BLOCK, 0, stream>>>(
      coords, ws, (float4*)out, npix);
}

// Round 5
// 120.389 us; speedup vs baseline: 4.5931x; 2.1533x over previous
//
#include <hip/hip_runtime.h>
#include <math.h>

// CoordinateDecoder via f16 MFMA (v_mfma_f32_32x32x16_f16).
// Formulation per layer: C[j][px] = W[j][k] * act[k][px]  (A=weights, B=act).
// C/D layout (verified m74/m101): col=lane&31 (pixel), row=(r&3)+8*(r>>2)+4*(lane>>5).
// A/B layout: row(col)=lane&31, k=(lane>>5)*8+reg.
// Pixel stays in the same lane column across layers -> layer transition is a
// half-wave __shfl_xor(32) + static selects. No LDS. Weights pre-packed into
// per-lane A-fragments (f16) by prep_kernel; cond-half of every layer folded
// into fp32 accumulator-init biases.

typedef _Float16 half8 __attribute__((ext_vector_type(8)));
typedef float f32x16 __attribute__((ext_vector_type(16)));

#define SCALE1 0.0790569415042094833f  // 1/sqrt(160)
#define SCALE2 0.0721687836487032206f  // 1/sqrt(192)
#define SQRT2F 1.41421356237309515f

// fragment region: half8 entries (16B each). tile entry = (mt*Kt+kt)*64+lane
#define FE_L1 0      // Mt=2, Kt=2 -> 4*64   entries
#define FE_L2 256    // Mt=2, Kt=4 -> 8*64
#define FE_L3 768    // Mt=2, Kt=4 -> 8*64
#define FE_L4 1280   // Mt=1, Kt=4 -> 4*64   (rows j>=4 zeroed)
// total 1536 entries = 24576 B = 6144 floats
#define OFF_CB1 6144   // [8][64] fp32 cond bias (incl b1)
#define OFF_CB2 6656
#define OFF_CB3 7168
#define OFF_CB4 7680   // [8][4]
// total 7712 floats = 30848 B

__global__ __launch_bounds__(256) void prep_kernel(
    const float* __restrict__ c, const float* __restrict__ fu,
    const float* __restrict__ w1, const float* __restrict__ b1,
    const float* __restrict__ w2, const float* __restrict__ b2,
    const float* __restrict__ w3, const float* __restrict__ b3,
    const float* __restrict__ w4, const float* __restrict__ b4,
    float* __restrict__ ws)
{
  int t = blockIdx.x * 256 + threadIdx.x;
  if (t < 12288) {
    // weight A-fragment packing, f16
    _Float16* fr = (_Float16*)ws;
    int e, mt, kt, Ktm;
    const float* w; float scale; int stride;
    if (t < 2048)       { e = t;         Ktm = 2; w = w1; scale = SCALE1; stride = 160; }
    else if (t < 6144)  { e = t - 2048;  Ktm = 4; w = w2; scale = SCALE2; stride = 192; }
    else if (t < 10240) { e = t - 6144;  Ktm = 4; w = w3; scale = SCALE2; stride = 192; }
    else                { e = t - 10240; Ktm = 4; w = w4; scale = SCALE2; stride = 192; }
    int til  = e >> 9;           // (mt*Kt+kt)
    int lane = (e >> 3) & 63;
    int r    = e & 7;
    mt = til / Ktm; kt = til - mt * Ktm;
    int j = 32 * mt + (lane & 31);
    int k = 16 * kt + ((lane >> 5) << 3) + r;
    float val;
    if (t < 2048) {
      // progressive frequency mask folded into w1 (k in [0,32))
      float mw = (fu[0] - (float)((k >> 2) + 1) * (1.0f / 9.0f)) * 9.0f;
      mw = fminf(fmaxf(mw, 0.0f), 1.0f);
      val = w[j * stride + k] * scale * mw;
    } else if (t >= 10240) {
      val = (j < 4) ? w[j * stride + k] * scale : 0.0f;  // mt==0 only
    } else {
      val = w[j * stride + k] * scale;
    }
    fr[t] = (_Float16)val;
  } else if (t < 12288 + 1568) {
    // per-(batch, output) conditioning dot products (fp32)
    int u = t - 12288;
    int b = u / 196, r = u - b * 196;
    const float* cb = c + b * 128;
    float acc;
    if (r < 64) {
      acc = b1[r];
      const float* wr = w1 + r * 160 + 32;
      #pragma unroll 8
      for (int k = 0; k < 128; ++k) acc = fmaf(wr[k] * SCALE1, cb[k], acc);
      ws[OFF_CB1 + b * 64 + r] = acc;
    } else if (r < 128) {
      int j = r - 64;
      acc = b2[j];
      const float* wr = w2 + j * 192 + 64;
      #pragma unroll 8
      for (int k = 0; k < 128; ++k) acc = fmaf(wr[k] * SCALE2, cb[k], acc);
      ws[OFF_CB2 + b * 64 + j] = acc;
    } else if (r < 192) {
      int j = r - 128;
      acc = b3[j];
      const float* wr = w3 + j * 192 + 64;
      #pragma unroll 8
      for (int k = 0; k < 128; ++k) acc = fmaf(wr[k] * SCALE2, cb[k], acc);
      ws[OFF_CB3 + b * 64 + j] = acc;
    } else {
      int j = r - 192;
      acc = b4[j];
      const float* wr = w4 + j * 192 + 64;
      #pragma unroll 8
      for (int k = 0; k < 128; ++k) acc = fmaf(wr[k] * SCALE2, cb[k], acc);
      ws[OFF_CB4 + b * 4 + j] = acc;
    }
  }
}

#define JROW(q, r) ((((r) & 3)) + 8 * ((r) >> 2) + 4 * (q))

__global__ __launch_bounds__(256, 2) void decoder_main(
    const float2* __restrict__ coords, const float* __restrict__ ws,
    float4* __restrict__ out)
{
  const int lane = threadIdx.x & 63;
  const int wave = threadIdx.x >> 6;
  const int base = blockIdx.x * 256 + wave * 64;  // 64 px per wave
  const int b    = base >> 16;                    // batch image (block-uniform)
  const int col  = lane & 31;
  const bool hi  = lane >= 32;                    // q = lane>>5

  const half8* __restrict__ frags = (const half8*)ws;
  const float* __restrict__ cb1 = ws + OFF_CB1 + b * 64;
  const float* __restrict__ cb2 = ws + OFF_CB2 + b * 64;
  const float* __restrict__ cb3 = ws + OFF_CB3 + b * 64;
  const float* __restrict__ cb4 = ws + OFF_CB4 + b * 4;

  const int p0 = base + col, p1 = base + 32 + col;
  const float2 cc0 = coords[p0];
  const float2 cc1 = coords[p1];

  // ---- layer-1 B fragments: sinusoidal embedding, computed in-register ----
  // channel c = 16*kt + 8*q + r;  type=(r&3): [sin x, sin y, cos x, cos y];
  // freq exponent f = 4*kt + 2*q + (r>>2);  angle = coord*0.1*2^f
  half8 bf[2][4];  // [nt][kt]  (only [.][0..1] used for layer 1)
  {
    const float qm = hi ? 0.4f : 0.1f;
    const float xs0 = cc0.x * qm, ys0 = cc0.y * qm;
    const float xs1 = cc1.x * qm, ys1 = cc1.y * qm;
    #pragma unroll
    for (int kt = 0; kt < 2; ++kt) {
      #pragma unroll
      for (int r = 0; r < 8; ++r) {
        const float mul = (float)(1 << (4 * kt + (r >> 2)));
        float a0, a1;
        if      ((r & 3) == 0) { a0 = __sinf(xs0 * mul); a1 = __sinf(xs1 * mul); }
        else if ((r & 3) == 1) { a0 = __sinf(ys0 * mul); a1 = __sinf(ys1 * mul); }
        else if ((r & 3) == 2) { a0 = __cosf(xs0 * mul); a1 = __cosf(xs1 * mul); }
        else                   { a0 = __cosf(ys0 * mul); a1 = __cosf(ys1 * mul); }
        bf[0][kt][r] = (_Float16)a0;
        bf[1][kt][r] = (_Float16)a1;
      }
    }
  }

  f32x16 acc[2][2];  // [mt][nt]
  half8 nbf[2][4];

  // transition: lrelu, half-wave exchange, repack acc -> next-layer B frags
  auto transition = [&]() {
    #pragma unroll
    for (int mt = 0; mt < 2; ++mt)
      #pragma unroll
      for (int nt = 0; nt < 2; ++nt) {
        float av[16], pv[16];
        #pragma unroll
        for (int r = 0; r < 16; ++r) {
          float v = acc[mt][nt][r];
          av[r] = (v > 0.0f ? v : 0.2f * v) * SQRT2F;
        }
        #pragma unroll
        for (int r = 0; r < 16; ++r) pv[r] = __shfl_xor(av[r], 32, 64);
        #pragma unroll
        for (int h2 = 0; h2 < 2; ++h2) {
          const int h = 8 * h2;
          half8 f;
          f[0] = (_Float16)(hi ? pv[4 + h] : av[0 + h]);
          f[1] = (_Float16)(hi ? pv[5 + h] : av[1 + h]);
          f[2] = (_Float16)(hi ? pv[6 + h] : av[2 + h]);
          f[3] = (_Float16)(hi ? pv[7 + h] : av[3 + h]);
          f[4] = (_Float16)(hi ? av[4 + h] : pv[0 + h]);
          f[5] = (_Float16)(hi ? av[5 + h] : pv[1 + h]);
          f[6] = (_Float16)(hi ? av[6 + h] : pv[2 + h]);
          f[7] = (_Float16)(hi ? av[7 + h] : pv[3 + h]);
          nbf[nt][2 * mt + h2] = f;
        }
      }
  };

  // ================= layer 1: K=32 (Kt=2) =================
  #pragma unroll
  for (int mt = 0; mt < 2; ++mt)
    #pragma unroll
    for (int r = 0; r < 16; ++r) {
      float bv = hi ? cb1[32 * mt + JROW(1, r)] : cb1[32 * mt + JROW(0, r)];
      acc[mt][0][r] = bv; acc[mt][1][r] = bv;
    }
  #pragma unroll
  for (int kt = 0; kt < 2; ++kt) {
    half8 a0 = frags[FE_L1 + (0 * 2 + kt) * 64 + lane];
    half8 a1 = frags[FE_L1 + (1 * 2 + kt) * 64 + lane];
    acc[0][0] = __builtin_amdgcn_mfma_f32_32x32x16_f16(a0, bf[0][kt], acc[0][0], 0, 0, 0);
    acc[0][1] = __builtin_amdgcn_mfma_f32_32x32x16_f16(a0, bf[1][kt], acc[0][1], 0, 0, 0);
    acc[1][0] = __builtin_amdgcn_mfma_f32_32x32x16_f16(a1, bf[0][kt], acc[1][0], 0, 0, 0);
    acc[1][1] = __builtin_amdgcn_mfma_f32_32x32x16_f16(a1, bf[1][kt], acc[1][1], 0, 0, 0);
  }

  transition();

  // ================= layers 2,3: K=64 (Kt=4) =================
  #pragma unroll
  for (int layer = 0; layer < 2; ++layer) {
    const int fe = layer == 0 ? FE_L2 : FE_L3;
    const float* __restrict__ cb = layer == 0 ? cb2 : cb3;
    #pragma unroll
    for (int mt = 0; mt < 2; ++mt)
      #pragma unroll
      for (int r = 0; r < 16; ++r) {
        float bv = hi ? cb[32 * mt + JROW(1, r)] : cb[32 * mt + JROW(0, r)];
        acc[mt][0][r] = bv; acc[mt][1][r] = bv;
      }
    #pragma unroll
    for (int kt = 0; kt < 4; ++kt) {
      half8 a0 = frags[fe + (0 * 4 + kt) * 64 + lane];
      half8 a1 = frags[fe + (1 * 4 + kt) * 64 + lane];
      acc[0][0] = __builtin_amdgcn_mfma_f32_32x32x16_f16(a0, nbf[0][kt], acc[0][0], 0, 0, 0);
      acc[0][1] = __builtin_amdgcn_mfma_f32_32x32x16_f16(a0, nbf[1][kt], acc[0][1], 0, 0, 0);
      acc[1][0] = __builtin_amdgcn_mfma_f32_32x32x16_f16(a1, nbf[0][kt], acc[1][0], 0, 0, 0);
      acc[1][1] = __builtin_amdgcn_mfma_f32_32x32x16_f16(a1, nbf[1][kt], acc[1][1], 0, 0, 0);
    }
    transition();
  }

  // ================= layer 4: 64 -> 4 =================
  f32x16 acc4[2];
  #pragma unroll
  for (int r = 0; r < 16; ++r) {
    float bv = (!hi && r < 4) ? cb4[r] : 0.0f;
    acc4[0][r] = bv; acc4[1][r] = bv;
  }
  #pragma unroll
  for (int kt = 0; kt < 4; ++kt) {
    half8 a0 = frags[FE_L4 + kt * 64 + lane];
    acc4[0] = __builtin_amdgcn_mfma_f32_32x32x16_f16(a0, nbf[0][kt], acc4[0], 0, 0, 0);
    acc4[1] = __builtin_amdgcn_mfma_f32_32x32x16_f16(a0, nbf[1][kt], acc4[1], 0, 0, 0);
  }

  // epilogue: lanes 0..31 hold channels j=0..3 in regs 0..3
  if (!hi) {
    #pragma unroll
    for (int nt = 0; nt < 2; ++nt) {
      const float2 cc = nt ? cc1 : cc0;
      const float rad = sqrtf(cc.x * cc.x + cc.y * cc.y);
      const float tt = fmaxf(rad - 1.0f, 0.0f);
      const float m = 2.0f / (__expf(2.0f * tt) + 1.0f);
      out[nt ? p1 : p0] = make_float4(acc4[nt][0] * m, acc4[nt][1] * m,
                                      acc4[nt][2] * m, acc4[nt][3] * m);
    }
  }
}

extern "C" void kernel_launch(void* const* d_in, const int* in_sizes, int n_in,
                              void* d_out, int out_size, void* d_ws, size_t ws_size,
                              hipStream_t stream) {
  const float* coords = (const float*)d_in[0];
  const float* c      = (const float*)d_in[1];
  const float* fu     = (const float*)d_in[2];
  const float* w1     = (const float*)d_in[3];
  const float* b1     = (const float*)d_in[4];
  const float* w2     = (const float*)d_in[5];
  const float* b2     = (const float*)d_in[6];
  const float* w3     = (const float*)d_in[7];
  const float* b3     = (const float*)d_in[8];
  const float* w4     = (const float*)d_in[9];
  const float* b4     = (const float*)d_in[10];
  float* ws  = (float*)d_ws;
  float* out = (float*)d_out;

  int npix = in_sizes[0] / 2;  // 8*256*256 = 524288

  prep_kernel<<<55, 256, 0, stream>>>(c, fu, w1, b1, w2, b2, w3, b3, w4, b4, ws);
  decoder_main<<<npix / 256, 256, 0, stream>>>(
      (const float2*)coords, ws, (float4*)out);
}

// Round 7
// 97.438 us; speedup vs baseline: 5.6750x; 1.2355x over previous
//
#include <hip/hip_runtime.h>
#include <math.h>

// CoordinateDecoder via f16 MFMA (v_mfma_f32_32x32x16_f16).
// R6: k-axis permutation trick — B-operand channel order is chosen so the
// MFMA C/D register layout IS the next layer's B-fragment layout:
//   pi(16kt+8q+reg) = 32(kt>>1)+16(kt&1)+8(reg>>2)+4q+(reg&3)
// (folded into prep's A-fragment packing). Layer transition = lrelu +
// cvt_pkrtz, no cross-lane ops. sqrt(2) of fused_lrelu folded into the next
// layer's pixel-half weights. Cond halves of all layers precomputed as fp32
// accumulator-init biases (float4-loadable layout).

typedef _Float16 half2v __attribute__((ext_vector_type(2)));
typedef __fp16   fp16x2 __attribute__((ext_vector_type(2)));
typedef _Float16 half4v __attribute__((ext_vector_type(4)));
typedef _Float16 half8  __attribute__((ext_vector_type(8)));
typedef float f32x16 __attribute__((ext_vector_type(16)));

#define SCALE1 0.0790569415042094833f  // 1/sqrt(160)
#define SCALE2 0.0721687836487032206f  // 1/sqrt(192)
#define SQRT2F 1.41421356237309515f

// fragment region: half8 entries (16B each). tile entry = (mt*Kt+kt)*64+lane
#define FE_L1 0      // Mt=2, Kt=2 -> 4*64   entries
#define FE_L2 256    // Mt=2, Kt=4 -> 8*64
#define FE_L3 768    // Mt=2, Kt=4 -> 8*64
#define FE_L4 1280   // Mt=1, Kt=4 -> 4*64   (rows j>=4 zeroed)
// total 1536 entries = 24576 B = 6144 floats
#define OFF_CB1 6144   // [8][64] fp32 cond bias (incl b1)
#define OFF_CB2 6656
#define OFF_CB3 7168
#define OFF_CB4 7680   // [8][4]
// total 7712 floats = 30848 B

__global__ __launch_bounds__(256) void prep_kernel(
    const float* __restrict__ c, const float* __restrict__ fu,
    const float* __restrict__ w1, const float* __restrict__ b1,
    const float* __restrict__ w2, const float* __restrict__ b2,
    const float* __restrict__ w3, const float* __restrict__ b3,
    const float* __restrict__ w4, const float* __restrict__ b4,
    float* __restrict__ ws)
{
  int t = blockIdx.x * 256 + threadIdx.x;
  if (t < 12288) {
    // weight A-fragment packing, f16
    _Float16* fr = (_Float16*)ws;
    int e, Ktm;
    const float* w; float scale; int stride; bool perm;
    if (t < 2048)       { e = t;         Ktm = 2; w = w1; scale = SCALE1;          stride = 160; perm = false; }
    else if (t < 6144)  { e = t - 2048;  Ktm = 4; w = w2; scale = SCALE2 * SQRT2F; stride = 192; perm = true;  }
    else if (t < 10240) { e = t - 6144;  Ktm = 4; w = w3; scale = SCALE2 * SQRT2F; stride = 192; perm = true;  }
    else                { e = t - 10240; Ktm = 4; w = w4; scale = SCALE2 * SQRT2F; stride = 192; perm = true;  }
    int til  = e >> 9;           // (mt*Kt+kt)
    int lane = (e >> 3) & 63;
    int r    = e & 7;            // reg within half8
    int q    = lane >> 5;
    int mt = til / Ktm, kt = til - mt * Ktm;
    int j = 32 * mt + (lane & 31);
    int k;
    if (perm) {
      // pi(16kt+8q+reg): channel order matching C/D register layout
      k = 32 * (kt >> 1) + 16 * (kt & 1) + 8 * (r >> 2) + 4 * q + (r & 3);
    } else {
      k = 16 * kt + 8 * q + r;   // layer-1 embedding order (identity)
    }
    float val;
    if (t < 2048) {
      // progressive frequency mask folded into w1 (k in [0,32))
      float mw = (fu[0] - (float)((k >> 2) + 1) * (1.0f / 9.0f)) * 9.0f;
      mw = fminf(fmaxf(mw, 0.0f), 1.0f);
      val = w[j * stride + k] * scale * mw;
    } else if (t >= 10240) {
      val = (j < 4) ? w[j * stride + k] * scale : 0.0f;  // mt==0 only
    } else {
      val = w[j * stride + k] * scale;
    }
    fr[t] = (_Float16)val;
  } else if (t < 12288 + 2048) {
    // per-(batch, output) conditioning dot products (fp32), wave-uniform
    // groups: [0,512)=cb1, [512,1024)=cb2, [1024,1536)=cb3, [1536,1568)=cb4
    int u = t - 12288;
    int grp = u >> 9;
    const float* wr; float bias; float scale; int outoff;
    int b, j;
    if (grp < 3) {
      b = (u & 511) >> 6; j = u & 63;
      if (grp == 0)      { wr = w1 + j * 160 + 32; bias = b1[j]; scale = SCALE1; outoff = OFF_CB1 + b * 64 + j; }
      else if (grp == 1) { wr = w2 + j * 192 + 64; bias = b2[j]; scale = SCALE2; outoff = OFF_CB2 + b * 64 + j; }
      else               { wr = w3 + j * 192 + 64; bias = b3[j]; scale = SCALE2; outoff = OFF_CB3 + b * 64 + j; }
    } else {
      int u2 = u - 1536;
      if (u2 >= 32) return;
      b = u2 >> 2; j = u2 & 3;
      wr = w4 + j * 192 + 64; bias = b4[j]; scale = SCALE2; outoff = OFF_CB4 + b * 4 + j;
    }
    const float4* wv = (const float4*)wr;
    const float4* cv = (const float4*)(c + b * 128);
    float4 s = make_float4(0.f, 0.f, 0.f, 0.f);
    #pragma unroll
    for (int k = 0; k < 32; ++k) {
      float4 a = wv[k], d = cv[k];
      s.x = fmaf(a.x, d.x, s.x);
      s.y = fmaf(a.y, d.y, s.y);
      s.z = fmaf(a.z, d.z, s.z);
      s.w = fmaf(a.w, d.w, s.w);
    }
    float dot = (s.x + s.y) + (s.z + s.w);
    ws[outoff] = fmaf(scale, dot, bias);
  }
}

__global__ __launch_bounds__(256, 4) void decoder_main(
    const float2* __restrict__ coords, const float* __restrict__ ws,
    float4* __restrict__ out)
{
  const int lane = threadIdx.x & 63;
  const int wave = threadIdx.x >> 6;
  const int base = blockIdx.x * 256 + wave * 64;  // 64 px per wave
  const int b    = base >> 16;                    // batch image (block-uniform)
  const int col  = lane & 31;
  const bool hi  = lane >= 32;                    // q = lane>>5
  const int q4   = hi ? 4 : 0;

  const half8* __restrict__ frags = (const half8*)ws;
  const float* __restrict__ cb1 = ws + OFF_CB1 + b * 64;
  const float* __restrict__ cb2 = ws + OFF_CB2 + b * 64;
  const float* __restrict__ cb3 = ws + OFF_CB3 + b * 64;
  const float* __restrict__ cb4 = ws + OFF_CB4 + b * 4;

  const int p0 = base + col, p1 = base + 32 + col;
  const float2 cc0 = coords[p0];
  const float2 cc1 = coords[p1];

  // ---- layer-1 B fragments: sinusoidal embedding, in-register ----
  // channel = 16kt+8q+r; type=(r&3): [sin x, sin y, cos x, cos y];
  // freq exponent f = 4kt+2q+(r>>2); angle = coord*0.1*2^f
  half8 bf[2][2];  // [nt][kt]
  {
    const float qm = hi ? 0.4f : 0.1f;
    const float xs0 = cc0.x * qm, ys0 = cc0.y * qm;
    const float xs1 = cc1.x * qm, ys1 = cc1.y * qm;
    #pragma unroll
    for (int kt = 0; kt < 2; ++kt) {
      #pragma unroll
      for (int r = 0; r < 8; ++r) {
        const float mul = (float)(1 << (4 * kt + (r >> 2)));
        float a0, a1;
        if      ((r & 3) == 0) { a0 = __sinf(xs0 * mul); a1 = __sinf(xs1 * mul); }
        else if ((r & 3) == 1) { a0 = __sinf(ys0 * mul); a1 = __sinf(ys1 * mul); }
        else if ((r & 3) == 2) { a0 = __cosf(xs0 * mul); a1 = __cosf(xs1 * mul); }
        else                   { a0 = __cosf(ys0 * mul); a1 = __cosf(ys1 * mul); }
        bf[0][kt][r] = (_Float16)a0;
        bf[1][kt][r] = (_Float16)a1;
      }
    }
  }

  f32x16 acc[2][2];  // [mt][nt]
  half8 nbf[2][4];   // [nt][kt] next-layer B frags

  // lrelu without sqrt2 (folded into next layer's weights)
  auto lrelu = [](float v) { return fmaxf(v, 0.2f * v); };

  // transition: lrelu + packed f16 convert; register layout already matches
  // the permuted B-fragment order (pi) — no cross-lane movement.
  auto transition = [&]() {
    #pragma unroll
    for (int mt = 0; mt < 2; ++mt)
      #pragma unroll
      for (int nt = 0; nt < 2; ++nt) {
        #pragma unroll
        for (int h = 0; h < 2; ++h) {
          half2v pp[4];
          #pragma unroll
          for (int p = 0; p < 4; ++p) {
            fp16x2 t = __builtin_amdgcn_cvt_pkrtz(
                lrelu(acc[mt][nt][8 * h + 2 * p]),
                lrelu(acc[mt][nt][8 * h + 2 * p + 1]));
            pp[p] = __builtin_bit_cast(half2v, t);
          }
          half4v q0 = __builtin_shufflevector(pp[0], pp[1], 0, 1, 2, 3);
          half4v q1 = __builtin_shufflevector(pp[2], pp[3], 0, 1, 2, 3);
          nbf[nt][2 * mt + h] = __builtin_shufflevector(q0, q1, 0, 1, 2, 3, 4, 5, 6, 7);
        }
      }
  };

  // acc init from cond-bias vector (float4 groups: rows 32mt+8g+4q+0..3)
  auto init_acc = [&](const float* __restrict__ cb) {
    #pragma unroll
    for (int mt = 0; mt < 2; ++mt)
      #pragma unroll
      for (int g = 0; g < 4; ++g) {
        const float4 f = *(const float4*)(cb + 32 * mt + 8 * g + q4);
        acc[mt][0][4 * g + 0] = f.x; acc[mt][1][4 * g + 0] = f.x;
        acc[mt][0][4 * g + 1] = f.y; acc[mt][1][4 * g + 1] = f.y;
        acc[mt][0][4 * g + 2] = f.z; acc[mt][1][4 * g + 2] = f.z;
        acc[mt][0][4 * g + 3] = f.w; acc[mt][1][4 * g + 3] = f.w;
      }
  };

  // ================= layer 1: K=32 (Kt=2) =================
  init_acc(cb1);
  #pragma unroll
  for (int kt = 0; kt < 2; ++kt) {
    half8 a0 = frags[FE_L1 + (0 * 2 + kt) * 64 + lane];
    half8 a1 = frags[FE_L1 + (1 * 2 + kt) * 64 + lane];
    acc[0][0] = __builtin_amdgcn_mfma_f32_32x32x16_f16(a0, bf[0][kt], acc[0][0], 0, 0, 0);
    acc[0][1] = __builtin_amdgcn_mfma_f32_32x32x16_f16(a0, bf[1][kt], acc[0][1], 0, 0, 0);
    acc[1][0] = __builtin_amdgcn_mfma_f32_32x32x16_f16(a1, bf[0][kt], acc[1][0], 0, 0, 0);
    acc[1][1] = __builtin_amdgcn_mfma_f32_32x32x16_f16(a1, bf[1][kt], acc[1][1], 0, 0, 0);
  }
  transition();

  // ================= layers 2,3: K=64 (Kt=4) =================
  #pragma unroll
  for (int layer = 0; layer < 2; ++layer) {
    const int fe = layer == 0 ? FE_L2 : FE_L3;
    init_acc(layer == 0 ? cb2 : cb3);
    #pragma unroll
    for (int kt = 0; kt < 4; ++kt) {
      half8 a0 = frags[fe + (0 * 4 + kt) * 64 + lane];
      half8 a1 = frags[fe + (1 * 4 + kt) * 64 + lane];
      acc[0][0] = __builtin_amdgcn_mfma_f32_32x32x16_f16(a0, nbf[0][kt], acc[0][0], 0, 0, 0);
      acc[0][1] = __builtin_amdgcn_mfma_f32_32x32x16_f16(a0, nbf[1][kt], acc[0][1], 0, 0, 0);
      acc[1][0] = __builtin_amdgcn_mfma_f32_32x32x16_f16(a1, nbf[0][kt], acc[1][0], 0, 0, 0);
      acc[1][1] = __builtin_amdgcn_mfma_f32_32x32x16_f16(a1, nbf[1][kt], acc[1][1], 0, 0, 0);
    }
    transition();
  }

  // ================= layer 4: 64 -> 4 =================
  f32x16 acc4[2];
  {
    const float4 f = *(const float4*)cb4;
    #pragma unroll
    for (int r = 0; r < 16; ++r) {
      float bv = (!hi && r < 4) ? ((const float*)&f)[r] : 0.0f;
      acc4[0][r] = bv; acc4[1][r] = bv;
    }
  }
  #pragma unroll
  for (int kt = 0; kt < 4; ++kt) {
    half8 a0 = frags[FE_L4 + kt * 64 + lane];
    acc4[0] = __builtin_amdgcn_mfma_f32_32x32x16_f16(a0, nbf[0][kt], acc4[0], 0, 0, 0);
    acc4[1] = __builtin_amdgcn_mfma_f32_32x32x16_f16(a0, nbf[1][kt], acc4[1], 0, 0, 0);
  }

  // epilogue: lanes 0..31 hold channels j=0..3 in regs 0..3
  if (!hi) {
    #pragma unroll
    for (int nt = 0; nt < 2; ++nt) {
      const float2 cc = nt ? cc1 : cc0;
      const float rad = sqrtf(cc.x * cc.x + cc.y * cc.y);
      const float tt = fmaxf(rad - 1.0f, 0.0f);
      const float m = 2.0f / (__expf(2.0f * tt) + 1.0f);
      out[nt ? p1 : p0] = make_float4(acc4[nt][0] * m, acc4[nt][1] * m,
                                      acc4[nt][2] * m, acc4[nt][3] * m);
    }
  }
}

extern "C" void kernel_launch(void* const* d_in, const int* in_sizes, int n_in,
                              void* d_out, int out_size, void* d_ws, size_t ws_size,
                              hipStream_t stream) {
  const float* coords = (const float*)d_in[0];
  const float* c      = (const float*)d_in[1];
  const float* fu     = (const float*)d_in[2];
  const float* w1     = (const float*)d_in[3];
  const float* b1     = (const float*)d_in[4];
  const float* w2     = (const float*)d_in[5];
  const float* b2     = (const float*)d_in[6];
  const float* w3     = (const float*)d_in[7];
  const float* b3     = (const float*)d_in[8];
  const float* w4     = (const float*)d_in[9];
  const float* b4     = (const float*)d_in[10];
  float* ws  = (float*)d_ws;
  float* out = (float*)d_out;

  int npix = in_sizes[0] / 2;  // 8*256*256 = 524288

  prep_kernel<<<56, 256, 0, stream>>>(c, fu, w1, b1, w2, b2, w3, b3, w4, b4, ws);
  decoder_main<<<npix / 256, 256, 0, stream>>>(
      (const float2*)coords, ws, (float4*)out);
}